// Round 1
// baseline (11927.860 us; speedup 1.0000x reference)
//
#include <hip/hip_runtime.h>
#include <stdint.h>

#define T_STEPS 512

typedef __bf16 bf16x8v __attribute__((ext_vector_type(8)));
typedef float f32x4 __attribute__((ext_vector_type(4)));
typedef unsigned short u16x8 __attribute__((ext_vector_type(8)));

__device__ __forceinline__ unsigned short f2bf(float f) {
    unsigned u = __float_as_uint(f);
    return (unsigned short)((u + 0x7fffu + ((u >> 16) & 1u)) >> 16);
}
__device__ __forceinline__ float bf2f(unsigned short s) {
    return __uint_as_float(((unsigned)s) << 16);
}

typedef __attribute__((address_space(1))) void as1_void;
typedef __attribute__((address_space(3))) void as3_void;

__device__ __forceinline__ void async16(const void* g, void* l) {
    __builtin_amdgcn_global_load_lds((as1_void*)(void*)g, (as3_void*)l, 16, 0, 0);
}
__device__ __forceinline__ void async4(const void* g, void* l) {
    __builtin_amdgcn_global_load_lds((as1_void*)(void*)g, (as3_void*)l, 4, 0, 0);
}

// ---------------- rowdot: out[r] = M[r, coff:coff+2048] . [h0|c0] (+b1+b2) ----
__global__ void k_rowdot(const float* __restrict__ M, int rs, int coff,
                         const float* __restrict__ h0, const float* __restrict__ c0,
                         const float* __restrict__ b1, const float* __restrict__ b2,
                         float* __restrict__ out, int nrows) {
    int wave = threadIdx.x >> 6, lane = threadIdx.x & 63;
    int r = blockIdx.x * 4 + wave;
    if (r >= nrows) return;
    const float* row = M + (long)r * rs + coff;
    float acc = 0.f;
#pragma unroll
    for (int it = 0; it < 8; ++it) {
        int k = it * 256 + lane * 4;
        float4 w = *(const float4*)(row + k);
        const float4* xp = (k < 1024) ? (const float4*)(h0 + k)
                                      : (const float4*)(c0 + (k - 1024));
        float4 x = *xp;
        acc += w.x * x.x + w.y * x.y + w.z * x.z + w.w * x.w;
    }
#pragma unroll
    for (int off = 32; off; off >>= 1) acc += __shfl_xor(acc, off, 64);
    if (lane == 0) {
        if (b1) acc += b1[r];
        if (b2) acc += b2[r];
        out[r] = acc;
    }
}

// ---------------- embedding gather -> bf16 into U[:,1024:1536] ----------------
__global__ void k_embs(const int* __restrict__ ids, const float* __restrict__ emb,
                       unsigned short* __restrict__ U) {
    int t = blockIdx.x, j = threadIdx.x;
    int id = ids[(t + T_STEPS - 1) & (T_STEPS - 1)];
    float2 v = *(const float2*)(emb + (long)id * 512 + j * 2);
    ushort2 s;
    s.x = f2bf(v.x); s.y = f2bf(v.y);
    *(ushort2*)(U + (long)t * 1536 + 1024 + j * 2) = s;
}

// ---------------- W_ih[:, :512] -> bf16 [4096][512] ---------------------------
__global__ void k_convW(const float* __restrict__ Wih, unsigned short* __restrict__ Wb) {
    int i = blockIdx.x * 256 + threadIdx.x;   // 524288 float4s
    int r = i >> 7, c4 = i & 127;
    float4 f = *(const float4*)(Wih + (long)r * 2560 + c4 * 4);
    ushort4 s;
    s.x = f2bf(f.x); s.y = f2bf(f.y); s.z = f2bf(f.z); s.w = f2bf(f.w);
    *(ushort4*)(Wb + (long)r * 512 + c4 * 4) = s;
}

// ---------------- [X|Y] -> bf16 V[32000][1536] --------------------------------
__global__ void k_convXY(const float* __restrict__ X, const float* __restrict__ Y,
                         unsigned short* __restrict__ V) {
    long i = (long)blockIdx.x * 256 + threadIdx.x;
    const long NX = (long)32000 * 256;
    if (i < NX) {
        long v = i >> 8; int c4 = (int)(i & 255);
        float4 f = *(const float4*)(X + v * 1024 + c4 * 4);
        ushort4 s;
        s.x = f2bf(f.x); s.y = f2bf(f.y); s.z = f2bf(f.z); s.w = f2bf(f.w);
        *(ushort4*)(V + v * 1536 + c4 * 4) = s;
    } else {
        i -= NX;
        long v = i >> 7; int c4 = (int)(i & 127);
        float4 f = *(const float4*)(Y + v * 512 + c4 * 4);
        ushort4 s;
        s.x = f2bf(f.x); s.y = f2bf(f.y); s.z = f2bf(f.z); s.w = f2bf(f.w);
        *(ushort4*)(V + v * 1536 + 1024 + c4 * 4) = s;
    }
}

// ---------------- m97-style bf16 MFMA GEMM, C = A·B^T + bias ------------------
// A [M][K] bf16 (lda), B [N][K] bf16 (ldb), C [M][N] f32 (ldc). M,N %128==0, K %32==0.
__global__ __launch_bounds__(256) void k_gemm_bt(
    const unsigned short* __restrict__ A, int lda,
    const unsigned short* __restrict__ B, int ldb,
    float* __restrict__ C, int ldc,
    const float* __restrict__ bias, int K) {
    __shared__ __align__(16) unsigned short As[128 * 32];
    __shared__ __align__(16) unsigned short Bs[128 * 32];
    const int tid = threadIdx.x;
    const long m0 = (long)blockIdx.y * 128, n0 = (long)blockIdx.x * 128;
    const int wave = tid >> 6, lane = tid & 63;
    const int wm = (wave >> 1) * 64, wn = (wave & 1) * 64;
    const int lm = lane & 15, lk = (lane >> 4) * 8;
    const int r0 = tid >> 2, r1 = (tid + 256) >> 2, kc = (tid & 3) * 8;
    const unsigned short* Ab = A + m0 * lda;
    const unsigned short* Bb = B + n0 * ldb;

    f32x4 acc[4][4];
#pragma unroll
    for (int i = 0; i < 4; ++i)
#pragma unroll
        for (int j = 0; j < 4; ++j) {
            f32x4 z = {0.f, 0.f, 0.f, 0.f};
            acc[i][j] = z;
        }

    for (int k0 = 0; k0 < K; k0 += 32) {
        async16(Ab + (long)r0 * lda + k0 + kc, &As[tid * 8]);
        async16(Ab + (long)r1 * lda + k0 + kc, &As[(tid + 256) * 8]);
        async16(Bb + (long)r0 * ldb + k0 + kc, &Bs[tid * 8]);
        async16(Bb + (long)r1 * ldb + k0 + kc, &Bs[(tid + 256) * 8]);
        __syncthreads();
        bf16x8v af[4], bfr[4];
#pragma unroll
        for (int t = 0; t < 4; ++t) af[t] = *(const bf16x8v*)&As[(wm + t * 16 + lm) * 32 + lk];
#pragma unroll
        for (int t = 0; t < 4; ++t) bfr[t] = *(const bf16x8v*)&Bs[(wn + t * 16 + lm) * 32 + lk];
#pragma unroll
        for (int i = 0; i < 4; ++i)
#pragma unroll
            for (int j = 0; j < 4; ++j)
                acc[i][j] = __builtin_amdgcn_mfma_f32_16x16x32_bf16(af[i], bfr[j], acc[i][j], 0, 0, 0);
        __syncthreads();
    }
    const int quad = lane >> 4;
#pragma unroll
    for (int j = 0; j < 4; ++j) {
        long col = n0 + wn + j * 16 + lm;
        float bv = bias ? bias[col] : 0.0f;
#pragma unroll
        for (int i = 0; i < 4; ++i)
#pragma unroll
            for (int rg = 0; rg < 4; ++rg) {
                long row = m0 + wm + i * 16 + quad * 4 + rg;
                C[row * (long)ldc + col] = acc[i][j][rg] + bv;
            }
    }
}

// ---------------- persistent LSTM scan ----------------------------------------
// 256 blocks, block b owns cell indices [4b,4b+4). W_hh rows q*1024+4b+jl (bf16 LDS).
// Per-step sync: per-block tag, agent-scope release store / acquire spin.
__global__ __launch_bounds__(256) void k_scan(
    const float* __restrict__ Whh, const float* __restrict__ gx,
    const float* __restrict__ h0, const float* __restrict__ c0,
    float* __restrict__ hbuf, unsigned short* __restrict__ U,
    unsigned int* __restrict__ tags) {
    __shared__ __align__(16) unsigned short Wl[16 * 1024];
    __shared__ __align__(16) float hs[1024];
    __shared__ __align__(16) float gxb[32 * 16];
    __shared__ float gv[16];
    __shared__ float cl[4];
    const int b = blockIdx.x, tid = threadIdx.x;

    // one-time: stage this block's 16 W_hh rows into LDS as bf16
#pragma unroll
    for (int it = 0; it < 16; ++it) {
        int f4 = it * 256 + tid;
        int lr = f4 >> 8, c4 = f4 & 255;
        long grow = (long)((lr >> 2) * 1024 + b * 4 + (lr & 3));
        float4 wv = *(const float4*)(Whh + grow * 1024 + c4 * 4);
        ushort4 s;
        s.x = f2bf(wv.x); s.y = f2bf(wv.y); s.z = f2bf(wv.z); s.w = f2bf(wv.w);
        *(ushort4*)&Wl[lr * 1024 + c4 * 4] = s;
    }
    if (tid < 4) cl[tid] = c0[b * 4 + tid];

    const int lr = tid >> 4, seg = tid & 15;
    for (int t = 0; t < T_STEPS; ++t) {
        if ((t & 31) == 0) {   // pre-stage gates_x for steps t..t+31 (no ordering dep)
            int c = tid;
            async4(gx + (long)(t + (c >> 4)) * 4096 + ((c & 15) >> 2) * 1024 + b * 4 + (c & 3), &gxb[c]);
            c = tid + 256;
            async4(gx + (long)(t + (c >> 4)) * 4096 + ((c & 15) >> 2) * 1024 + b * 4 + (c & 3), &gxb[c]);
        }
        if (t > 0) {
            unsigned tgt = (unsigned)t;
            while (__hip_atomic_load(&tags[tid], __ATOMIC_ACQUIRE, __HIP_MEMORY_SCOPE_AGENT) < tgt) {}
        }
        const float* hsrc = (t == 0) ? h0 : (hbuf + (t & 1) * 1024);
        async16(hsrc + tid * 4, &hs[tid * 4]);
        __syncthreads();   // drains global_load_lds (vmcnt) + LDS writes

        // matvec: thread (lr,seg) covers cols {u*128 + seg*8 + 0..7}
        float acc = 0.f;
#pragma unroll
        for (int u = 0; u < 8; ++u) {
            u16x8 w8 = *(const u16x8*)&Wl[lr * 1024 + u * 128 + seg * 8];
            float4 ha = *(const float4*)&hs[u * 128 + seg * 8];
            float4 hb = *(const float4*)&hs[u * 128 + seg * 8 + 4];
            acc += bf2f(w8[0]) * ha.x + bf2f(w8[1]) * ha.y + bf2f(w8[2]) * ha.z + bf2f(w8[3]) * ha.w
                 + bf2f(w8[4]) * hb.x + bf2f(w8[5]) * hb.y + bf2f(w8[6]) * hb.z + bf2f(w8[7]) * hb.w;
        }
#pragma unroll
        for (int off = 1; off < 16; off <<= 1) acc += __shfl_xor(acc, off, 64);
        if (seg == 0) gv[lr] = acc;
        __syncthreads();

        if (tid < 4) {
            int sl = (t & 31) * 16;
            float ig = gv[tid]      + gxb[sl + tid];
            float fg = gv[4 + tid]  + gxb[sl + 4 + tid];
            float gg = gv[8 + tid]  + gxb[sl + 8 + tid];
            float og = gv[12 + tid] + gxb[sl + 12 + tid];
            float si = 1.f / (1.f + expf(-ig));
            float sf = 1.f / (1.f + expf(-fg));
            float so = 1.f / (1.f + expf(-og));
            float cn = sf * cl[tid] + si * tanhf(gg);
            float hn = so * tanhf(cn);
            cl[tid] = cn;
            hbuf[((t + 1) & 1) * 1024 + b * 4 + tid] = hn;
            U[(long)t * 1536 + b * 4 + tid] = f2bf(hn);
        }
        __syncthreads();   // drains h stores (vmcnt) for all threads
        if (tid == 0)
            __hip_atomic_store(&tags[b], (unsigned)(t + 1), __ATOMIC_RELEASE, __HIP_MEMORY_SCOPE_AGENT);
    }
}

extern "C" void kernel_launch(void* const* d_in, const int* in_sizes, int n_in,
                              void* d_out, int out_size, void* d_ws, size_t ws_size,
                              hipStream_t stream) {
    const float* h0  = (const float*)d_in[0];
    const float* c0  = (const float*)d_in[1];
    const int*   ids = (const int*)d_in[2];
    const float* emb = (const float*)d_in[3];
    const float* Wih = (const float*)d_in[4];
    const float* Whh = (const float*)d_in[5];
    const float* bih = (const float*)d_in[6];
    const float* bhh = (const float*)d_in[7];
    const float* X   = (const float*)d_in[8];
    const float* Y   = (const float*)d_in[9];
    const float* Z   = (const float*)d_in[10];
    float* out = (float*)d_out;

    char* ws = (char*)d_ws;
    size_t off = 0;
    auto take = [&](size_t bytes) -> char* {
        char* p = ws + off;
        off = (off + bytes + 511) & ~(size_t)511;
        return p;
    };
    unsigned int* tags   = (unsigned int*)take(256 * 4);
    float* hbuf          = (float*)take(2 * 1024 * 4);
    float* wf            = (float*)take(4096 * 4);
    float* zf            = (float*)take(32000 * 4);
    unsigned short* U    = (unsigned short*)take((size_t)512 * 1536 * 2);
    unsigned short* Wihb = (unsigned short*)take((size_t)4096 * 512 * 2);
    float* gatesx        = (float*)take((size_t)512 * 4096 * 4);
    unsigned short* Vbf  = (unsigned short*)take((size_t)32000 * 1536 * 2);
    (void)in_sizes; (void)n_in; (void)out_size; (void)ws_size;

    hipMemsetAsync(tags, 0, 256 * 4, stream);
    // wf = W_ih[:,512:]@[h0|c0] + b_ih + b_hh ; zf = Z@[h0|c0]
    k_rowdot<<<1024, 256, 0, stream>>>(Wih, 2560, 512, h0, c0, bih, bhh, wf, 4096);
    k_rowdot<<<8000, 256, 0, stream>>>(Z, 2048, 0, h0, c0, nullptr, nullptr, zf, 32000);
    k_embs<<<512, 256, 0, stream>>>(ids, emb, U);
    k_convW<<<2048, 256, 0, stream>>>(Wih, Wihb);
    // gates_x[t][r] = emb_bf[t]·Wihb[r] + wf[r]
    k_gemm_bt<<<dim3(32, 4), 256, 0, stream>>>(U + 1024, 1536, Wihb, 512, gatesx, 4096, wf, 512);
    k_convXY<<<48000, 256, 0, stream>>>(X, Y, Vbf);
    k_scan<<<256, 256, 0, stream>>>(Whh, gatesx, h0, c0, hbuf, U, tags);
    // scores = [hs|emb]·[X|Y]^T + zf
    k_gemm_bt<<<dim3(250, 4), 256, 0, stream>>>(U, 1536, Vbf, 1536, out, 32000, zf, 1536);
}

// Round 2
// 2389.488 us; speedup vs baseline: 4.9918x; 4.9918x over previous
//
#include <hip/hip_runtime.h>
#include <stdint.h>

#define T_STEPS 512

typedef __bf16 bf16x8v __attribute__((ext_vector_type(8)));
typedef float f32x4 __attribute__((ext_vector_type(4)));
typedef unsigned short u16x8 __attribute__((ext_vector_type(8)));

__device__ __forceinline__ unsigned short f2bf(float f) {
    unsigned u = __float_as_uint(f);
    return (unsigned short)((u + 0x7fffu + ((u >> 16) & 1u)) >> 16);
}

typedef __attribute__((address_space(1))) void as1_void;
typedef __attribute__((address_space(3))) void as3_void;

__device__ __forceinline__ void async16(const void* g, void* l) {
    __builtin_amdgcn_global_load_lds((as1_void*)(void*)g, (as3_void*)l, 16, 0, 0);
}
__device__ __forceinline__ void async4(const void* g, void* l) {
    __builtin_amdgcn_global_load_lds((as1_void*)(void*)g, (as3_void*)l, 4, 0, 0);
}

// ---------------- rowdot: out[r] = M[r, coff:coff+2048] . [h0|c0] (+b1+b2) ----
__global__ void k_rowdot(const float* __restrict__ M, int rs, int coff,
                         const float* __restrict__ h0, const float* __restrict__ c0,
                         const float* __restrict__ b1, const float* __restrict__ b2,
                         float* __restrict__ out, int nrows) {
    int wave = threadIdx.x >> 6, lane = threadIdx.x & 63;
    int r = blockIdx.x * 4 + wave;
    if (r >= nrows) return;
    const float* row = M + (long)r * rs + coff;
    float acc = 0.f;
#pragma unroll
    for (int it = 0; it < 8; ++it) {
        int k = it * 256 + lane * 4;
        float4 w = *(const float4*)(row + k);
        const float4* xp = (k < 1024) ? (const float4*)(h0 + k)
                                      : (const float4*)(c0 + (k - 1024));
        float4 x = *xp;
        acc += w.x * x.x + w.y * x.y + w.z * x.z + w.w * x.w;
    }
#pragma unroll
    for (int off = 32; off; off >>= 1) acc += __shfl_xor(acc, off, 64);
    if (lane == 0) {
        if (b1) acc += b1[r];
        if (b2) acc += b2[r];
        out[r] = acc;
    }
}

// ---------------- embedding gather -> bf16 into U[:,1024:1536] ----------------
__global__ void k_embs(const int* __restrict__ ids, const float* __restrict__ emb,
                       unsigned short* __restrict__ U) {
    int t = blockIdx.x, j = threadIdx.x;
    int id = ids[(t + T_STEPS - 1) & (T_STEPS - 1)];
    float2 v = *(const float2*)(emb + (long)id * 512 + j * 2);
    ushort2 s;
    s.x = f2bf(v.x); s.y = f2bf(v.y);
    *(ushort2*)(U + (long)t * 1536 + 1024 + j * 2) = s;
}

// ---------------- W_ih[:, :512] -> bf16 [4096][512] ---------------------------
__global__ void k_convW(const float* __restrict__ Wih, unsigned short* __restrict__ Wb) {
    int i = blockIdx.x * 256 + threadIdx.x;   // 524288 float4s
    int r = i >> 7, c4 = i & 127;
    float4 f = *(const float4*)(Wih + (long)r * 2560 + c4 * 4);
    ushort4 s;
    s.x = f2bf(f.x); s.y = f2bf(f.y); s.z = f2bf(f.z); s.w = f2bf(f.w);
    *(ushort4*)(Wb + (long)r * 512 + c4 * 4) = s;
}

// ---------------- [X|Y] -> bf16 V[32000][1536] --------------------------------
__global__ void k_convXY(const float* __restrict__ X, const float* __restrict__ Y,
                         unsigned short* __restrict__ V) {
    long i = (long)blockIdx.x * 256 + threadIdx.x;
    const long NX = (long)32000 * 256;
    if (i < NX) {
        long v = i >> 8; int c4 = (int)(i & 255);
        float4 f = *(const float4*)(X + v * 1024 + c4 * 4);
        ushort4 s;
        s.x = f2bf(f.x); s.y = f2bf(f.y); s.z = f2bf(f.z); s.w = f2bf(f.w);
        *(ushort4*)(V + v * 1536 + c4 * 4) = s;
    } else {
        i -= NX;
        long v = i >> 7; int c4 = (int)(i & 127);
        float4 f = *(const float4*)(Y + v * 512 + c4 * 4);
        ushort4 s;
        s.x = f2bf(f.x); s.y = f2bf(f.y); s.z = f2bf(f.z); s.w = f2bf(f.w);
        *(ushort4*)(V + v * 1536 + 1024 + c4 * 4) = s;
    }
}

// ---------------- m97-style bf16 MFMA GEMM, C = A·B^T + bias ------------------
__global__ __launch_bounds__(256) void k_gemm_bt(
    const unsigned short* __restrict__ A, int lda,
    const unsigned short* __restrict__ B, int ldb,
    float* __restrict__ C, int ldc,
    const float* __restrict__ bias, int K) {
    __shared__ __align__(16) unsigned short As[128 * 32];
    __shared__ __align__(16) unsigned short Bs[128 * 32];
    const int tid = threadIdx.x;
    const long m0 = (long)blockIdx.y * 128, n0 = (long)blockIdx.x * 128;
    const int wave = tid >> 6, lane = tid & 63;
    const int wm = (wave >> 1) * 64, wn = (wave & 1) * 64;
    const int lm = lane & 15, lk = (lane >> 4) * 8;
    const int r0 = tid >> 2, r1 = (tid + 256) >> 2, kc = (tid & 3) * 8;
    const unsigned short* Ab = A + m0 * lda;
    const unsigned short* Bb = B + n0 * ldb;

    f32x4 acc[4][4];
#pragma unroll
    for (int i = 0; i < 4; ++i)
#pragma unroll
        for (int j = 0; j < 4; ++j) {
            f32x4 z = {0.f, 0.f, 0.f, 0.f};
            acc[i][j] = z;
        }

    for (int k0 = 0; k0 < K; k0 += 32) {
        async16(Ab + (long)r0 * lda + k0 + kc, &As[tid * 8]);
        async16(Ab + (long)r1 * lda + k0 + kc, &As[(tid + 256) * 8]);
        async16(Bb + (long)r0 * ldb + k0 + kc, &Bs[tid * 8]);
        async16(Bb + (long)r1 * ldb + k0 + kc, &Bs[(tid + 256) * 8]);
        __syncthreads();
        bf16x8v af[4], bfr[4];
#pragma unroll
        for (int t = 0; t < 4; ++t) af[t] = *(const bf16x8v*)&As[(wm + t * 16 + lm) * 32 + lk];
#pragma unroll
        for (int t = 0; t < 4; ++t) bfr[t] = *(const bf16x8v*)&Bs[(wn + t * 16 + lm) * 32 + lk];
#pragma unroll
        for (int i = 0; i < 4; ++i)
#pragma unroll
            for (int j = 0; j < 4; ++j)
                acc[i][j] = __builtin_amdgcn_mfma_f32_16x16x32_bf16(af[i], bfr[j], acc[i][j], 0, 0, 0);
        __syncthreads();
    }
    const int quad = lane >> 4;
#pragma unroll
    for (int j = 0; j < 4; ++j) {
        long col = n0 + wn + j * 16 + lm;
        float bv = bias ? bias[col] : 0.0f;
#pragma unroll
        for (int i = 0; i < 4; ++i)
#pragma unroll
            for (int rg = 0; rg < 4; ++rg) {
                long row = m0 + wm + i * 16 + quad * 4 + rg;
                C[row * (long)ldc + col] = acc[i][j][rg] + bv;
            }
    }
}

// ---------------- persistent LSTM scan, fence-free exchange -------------------
// 256 blocks, block b owns cells [4b,4b+4) (16 gate rows). W_hh slice lives in
// 64 f32 VGPRs per thread. Per-step h exchange: 512 packed 64-bit words
// (2 x fp16 h | 32-bit step tag), double-buffered, RELAXED agent atomics only —
// data rides inside the atomic word, so no acquire/release cache maintenance.
__global__ __launch_bounds__(256) void k_scan(
    const float* __restrict__ Whh, const float* __restrict__ gx,
    const float* __restrict__ h0, const float* __restrict__ c0,
    unsigned long long* __restrict__ hx, unsigned short* __restrict__ U) {
    __shared__ __align__(16) float hs[1024];
    __shared__ __align__(16) float gxb[32 * 16];
    __shared__ float gv[16];
    const int b = blockIdx.x, tid = threadIdx.x;
    const int lr = tid >> 4, seg = tid & 15;

    // one-time: this thread's fixed W_hh slice -> 64 f32 registers.
    // row lr -> global gate row (lr>>2)*1024 + b*4 + (lr&3); cols u*128+seg*8+0..7
    const float* wrow = Whh + (long)((lr >> 2) * 1024 + b * 4 + (lr & 3)) * 1024;
    f32x4 wv[16];
#pragma unroll
    for (int u = 0; u < 8; ++u) {
        wv[2 * u]     = *(const f32x4*)(wrow + u * 128 + seg * 8);
        wv[2 * u + 1] = *(const f32x4*)(wrow + u * 128 + seg * 8 + 4);
    }
    // cell state: thread 0 holds cells 0,1; thread 1 holds cells 2,3 (local idx)
    float cA = 0.f, cB = 0.f;
    if (tid < 2) { cA = c0[b * 4 + 2 * tid]; cB = c0[b * 4 + 2 * tid + 1]; }

    for (int t = 0; t < T_STEPS; ++t) {
        if ((t & 31) == 0) {   // pre-stage gates_x for steps t..t+31
            __syncthreads();   // protect gxb vs previous step's pointwise reads
            int c = tid;
            async4(gx + (long)(t + (c >> 4)) * 4096 + ((c & 15) >> 2) * 1024 + b * 4 + (c & 3), &gxb[c]);
            c = tid + 256;
            async4(gx + (long)(t + (c >> 4)) * 4096 + ((c & 15) >> 2) * 1024 + b * 4 + (c & 3), &gxb[c]);
        }
        if (t == 0) {
            float4 hv = *(const float4*)(h0 + tid * 4);
            *(float4*)&hs[tid * 4] = hv;
        } else {
            const unsigned long long* src = hx + (long)(t & 1) * 512 + tid * 2;
            unsigned long long w0, w1;
            do { w0 = __hip_atomic_load(src,     __ATOMIC_RELAXED, __HIP_MEMORY_SCOPE_AGENT); }
            while ((unsigned)(w0 >> 32) != (unsigned)t);
            do { w1 = __hip_atomic_load(src + 1, __ATOMIC_RELAXED, __HIP_MEMORY_SCOPE_AGENT); }
            while ((unsigned)(w1 >> 32) != (unsigned)t);
            union { unsigned u; _Float16 h[2]; } p0, p1;
            p0.u = (unsigned)w0; p1.u = (unsigned)w1;
            hs[tid * 4 + 0] = (float)p0.h[0];
            hs[tid * 4 + 1] = (float)p0.h[1];
            hs[tid * 4 + 2] = (float)p1.h[0];
            hs[tid * 4 + 3] = (float)p1.h[1];
        }
        __syncthreads();   // hs ready; also drains gxb async loads

        // matvec: thread (lr,seg) accumulates its 64-col slice of row lr
        float acc = 0.f;
#pragma unroll
        for (int u = 0; u < 8; ++u) {
            const f32x4 ha = *(const f32x4*)&hs[u * 128 + seg * 8];
            const f32x4 hb = *(const f32x4*)&hs[u * 128 + seg * 8 + 4];
            const f32x4 wa = wv[2 * u], wb = wv[2 * u + 1];
            acc += wa[0] * ha[0] + wa[1] * ha[1] + wa[2] * ha[2] + wa[3] * ha[3]
                 + wb[0] * hb[0] + wb[1] * hb[1] + wb[2] * hb[2] + wb[3] * hb[3];
        }
#pragma unroll
        for (int off = 1; off < 16; off <<= 1) acc += __shfl_xor(acc, off, 64);
        if (seg == 0) gv[lr] = acc;
        __syncthreads();

        if (tid < 2) {
            const int sl = (t & 31) * 16;
            union { unsigned u; _Float16 h[2]; } pk;
            unsigned short ub[2];
            float cc[2] = {cA, cB};
#pragma unroll
            for (int q = 0; q < 2; ++q) {
                const int j = 2 * tid + q;
                float ig = gv[j]      + gxb[sl + j];
                float fg = gv[4 + j]  + gxb[sl + 4 + j];
                float gg = gv[8 + j]  + gxb[sl + 8 + j];
                float og = gv[12 + j] + gxb[sl + 12 + j];
                float si = 1.f / (1.f + expf(-ig));
                float sf = 1.f / (1.f + expf(-fg));
                float so = 1.f / (1.f + expf(-og));
                float cn = sf * cc[q] + si * tanhf(gg);
                float hn = so * tanhf(cn);
                cc[q] = cn;
                pk.h[q] = (_Float16)hn;
                ub[q] = f2bf(hn);
            }
            cA = cc[0]; cB = cc[1];
            *(ushort2*)(U + (long)t * 1536 + b * 4 + 2 * tid) = *(ushort2*)ub;
            unsigned long long word = (unsigned long long)pk.u
                                    | ((unsigned long long)(unsigned)(t + 1) << 32);
            __hip_atomic_store(&hx[(long)((t + 1) & 1) * 512 + b * 2 + tid], word,
                               __ATOMIC_RELAXED, __HIP_MEMORY_SCOPE_AGENT);
        }
        // no barrier needed here: hs is only overwritten after the next
        // iteration's poll, which follows this step's matvec reads (all
        // threads passed the post-matvec __syncthreads before polling).
    }
}

extern "C" void kernel_launch(void* const* d_in, const int* in_sizes, int n_in,
                              void* d_out, int out_size, void* d_ws, size_t ws_size,
                              hipStream_t stream) {
    const float* h0  = (const float*)d_in[0];
    const float* c0  = (const float*)d_in[1];
    const int*   ids = (const int*)d_in[2];
    const float* emb = (const float*)d_in[3];
    const float* Wih = (const float*)d_in[4];
    const float* Whh = (const float*)d_in[5];
    const float* bih = (const float*)d_in[6];
    const float* bhh = (const float*)d_in[7];
    const float* X   = (const float*)d_in[8];
    const float* Y   = (const float*)d_in[9];
    const float* Z   = (const float*)d_in[10];
    float* out = (float*)d_out;

    char* ws = (char*)d_ws;
    size_t off = 0;
    auto take = [&](size_t bytes) -> char* {
        char* p = ws + off;
        off = (off + bytes + 511) & ~(size_t)511;
        return p;
    };
    unsigned long long* hx = (unsigned long long*)take(2 * 512 * 8);
    float* wf            = (float*)take(4096 * 4);
    float* zf            = (float*)take(32000 * 4);
    unsigned short* U    = (unsigned short*)take((size_t)512 * 1536 * 2);
    unsigned short* Wihb = (unsigned short*)take((size_t)4096 * 512 * 2);
    float* gatesx        = (float*)take((size_t)512 * 4096 * 4);
    unsigned short* Vbf  = (unsigned short*)take((size_t)32000 * 1536 * 2);
    (void)in_sizes; (void)n_in; (void)out_size; (void)ws_size;

    hipMemsetAsync(hx, 0, 2 * 512 * 8, stream);   // clear tags (poison could alias)
    // wf = W_ih[:,512:]@[h0|c0] + b_ih + b_hh ; zf = Z@[h0|c0]
    k_rowdot<<<1024, 256, 0, stream>>>(Wih, 2560, 512, h0, c0, bih, bhh, wf, 4096);
    k_rowdot<<<8000, 256, 0, stream>>>(Z, 2048, 0, h0, c0, nullptr, nullptr, zf, 32000);
    k_embs<<<512, 256, 0, stream>>>(ids, emb, U);
    k_convW<<<2048, 256, 0, stream>>>(Wih, Wihb);
    // gates_x[t][r] = emb_bf[t]·Wihb[r] + wf[r]
    k_gemm_bt<<<dim3(32, 4), 256, 0, stream>>>(U + 1024, 1536, Wihb, 512, gatesx, 4096, wf, 512);
    k_convXY<<<48000, 256, 0, stream>>>(X, Y, Vbf);
    k_scan<<<256, 256, 0, stream>>>(Whh, gatesx, h0, c0, hx, U);
    // scores = [hs|emb]·[X|Y]^T + zf
    k_gemm_bt<<<dim3(250, 4), 256, 0, stream>>>(U, 1536, Vbf, 1536, out, 32000, zf, 1536);
}